// Round 1
// baseline (1156.414 us; speedup 1.0000x reference)
//
#include <hip/hip_runtime.h>

#define NUSER 100000
#define NITEM 50000
#define NTOT  150000
#define DF    512
#define DL    64
#define NNZ_  2400000
#define CAP   64

// ---------------- W transpose: Wt[d][k] = W[k][d] ----------------
__global__ void k_wt(const float* __restrict__ W, float* __restrict__ Wt) {
    int idx = blockIdx.x * 256 + threadIdx.x;
    if (idx < DF * DL) {
        int k = idx / DL, d = idx % DL;
        Wt[d * DF + k] = W[idx];
    }
}

// ---------------- users: L2-normalize rows, init emb + out ----------------
__global__ __launch_bounds__(256) void k_user(const float* __restrict__ up,
                                              float* __restrict__ emb,
                                              float* __restrict__ outp) {
    int t = blockIdx.x * 256 + threadIdx.x;
    int r = t >> 6;
    if (r >= NUSER) return;
    float v = up[t];
    float ss = v * v;
    #pragma unroll
    for (int m = 32; m >= 1; m >>= 1) ss += __shfl_xor(ss, m, 64);
    float scale = 1.0f / fmaxf(sqrtf(ss), 1e-12f);
    float o = v * scale;
    emb[t]  = o;
    outp[t] = 0.25f * o;  // embs_sum/4 accumulator init
}

// ---------------- items: GEMM (64x64 tile, K=512) + bias + normalize ----------------
#define KCH 128
__global__ __launch_bounds__(256) void k_item(const float* __restrict__ F,
                                              const float* __restrict__ Wt,
                                              const float* __restrict__ B,
                                              float* __restrict__ emb,
                                              float* __restrict__ outp) {
    __shared__ float ft[64][132];  // padded: 132*4B stride breaks bank aliasing
    int t = threadIdx.x;
    int block_r0 = blockIdx.x * 64;
    int d0 = (t & 15) * 4;
    int r0 = (t >> 4) * 4;
    float acc[4][4] = {};
    for (int kc = 0; kc < DF; kc += KCH) {
        #pragma unroll
        for (int i = 0; i < 8; ++i) {
            int li  = t + i * 256;           // 0..2047 quads
            int row = li >> 5;               // 32 quads per row
            int kk  = (li & 31) * 4;
            int gr  = block_r0 + row;
            float4 v = make_float4(0.f, 0.f, 0.f, 0.f);
            if (gr < NITEM) v = *(const float4*)&F[(size_t)gr * DF + kc + kk];
            *(float4*)&ft[row][kk] = v;
        }
        __syncthreads();
        #pragma unroll 4
        for (int kk = 0; kk < KCH; kk += 4) {
            float4 w0 = *(const float4*)&Wt[(d0 + 0) * DF + kc + kk];
            float4 w1 = *(const float4*)&Wt[(d0 + 1) * DF + kc + kk];
            float4 w2 = *(const float4*)&Wt[(d0 + 2) * DF + kc + kk];
            float4 w3 = *(const float4*)&Wt[(d0 + 3) * DF + kc + kk];
            #pragma unroll
            for (int i = 0; i < 4; ++i) {
                float4 f = *(const float4*)&ft[r0 + i][kk];
                acc[i][0] += f.x * w0.x + f.y * w0.y + f.z * w0.z + f.w * w0.w;
                acc[i][1] += f.x * w1.x + f.y * w1.y + f.z * w1.z + f.w * w1.w;
                acc[i][2] += f.x * w2.x + f.y * w2.y + f.z * w2.z + f.w * w2.w;
                acc[i][3] += f.x * w3.x + f.y * w3.y + f.z * w3.z + f.w * w3.w;
            }
        }
        __syncthreads();
    }
    float b0 = B[d0], b1 = B[d0 + 1], b2 = B[d0 + 2], b3 = B[d0 + 3];
    #pragma unroll
    for (int i = 0; i < 4; ++i) {
        acc[i][0] += b0; acc[i][1] += b1; acc[i][2] += b2; acc[i][3] += b3;
        float ss = acc[i][0] * acc[i][0] + acc[i][1] * acc[i][1]
                 + acc[i][2] * acc[i][2] + acc[i][3] * acc[i][3];
        #pragma unroll
        for (int m = 8; m >= 1; m >>= 1) ss += __shfl_xor(ss, m, 64);  // 16 lanes/row
        float scale = 1.0f / fmaxf(sqrtf(ss), 1e-12f);
        int gr = block_r0 + r0 + i;
        if (gr < NITEM) {
            size_t o = (size_t)(NUSER + gr) * DL + d0;
            float4 v = make_float4(acc[i][0] * scale, acc[i][1] * scale,
                                   acc[i][2] * scale, acc[i][3] * scale);
            *(float4*)&emb[o] = v;
            float4 vo = make_float4(v.x * 0.25f, v.y * 0.25f, v.z * 0.25f, v.w * 0.25f);
            *(float4*)&outp[o] = vo;
        }
    }
}

// ---------------- bucket fill (fixed-capacity CSR substitute) ----------------
__global__ __launch_bounds__(256) void k_fill(const int* __restrict__ rows,
                                              const int* __restrict__ cols,
                                              const float* __restrict__ vals,
                                              int* __restrict__ cur,
                                              int* __restrict__ ecol,
                                              float* __restrict__ eval) {
    int e = blockIdx.x * 256 + threadIdx.x;
    if (e >= NNZ_) return;
    int r = rows[e];
    int pos = atomicAdd(&cur[r], 1);
    if (pos < CAP) {
        ecol[r * CAP + pos] = cols[e];
        eval[r * CAP + pos] = vals[e];
    }
}

// ---------------- SpMM layer: one wave per row, lane = dim ----------------
__global__ __launch_bounds__(256) void k_spmm(const int* __restrict__ cur,
                                              const int* __restrict__ ecol,
                                              const float* __restrict__ eval,
                                              const float* __restrict__ embIn,
                                              float* __restrict__ embOut,
                                              float* __restrict__ outp) {
    int t = blockIdx.x * 256 + threadIdx.x;
    int r = t >> 6, d = t & 63;
    if (r >= NTOT) return;
    int cnt  = min(cur[r], CAP);
    int base = r * CAP;
    float acc = 0.f;
    for (int j = 0; j < cnt; ++j) {
        int   c = ecol[base + j];
        float v = eval[base + j];
        acc += v * embIn[c * DL + d];
    }
    embOut[t] = acc;
    outp[t]  += 0.25f * acc;
}

extern "C" void kernel_launch(void* const* d_in, const int* in_sizes, int n_in,
                              void* d_out, int out_size, void* d_ws, size_t ws_size,
                              hipStream_t stream) {
    const float* F    = (const float*)d_in[0];
    const float* UP   = (const float*)d_in[1];
    const float* W    = (const float*)d_in[2];
    const float* B    = (const float*)d_in[3];
    const int*   rows = (const int*)d_in[4];
    const int*   cols = (const int*)d_in[5];
    const float* vals = (const float*)d_in[6];
    float* out = (float*)d_out;

    // workspace carve (~154 MB)
    float* embA = (float*)d_ws;
    float* embB = embA + (size_t)NTOT * DL;
    int*   cur  = (int*)(embB + (size_t)NTOT * DL);
    int*   ecol = cur + NTOT;
    float* eval = (float*)(ecol + (size_t)NTOT * CAP);
    float* Wt   = eval + (size_t)NTOT * CAP;

    hipMemsetAsync(cur, 0, NTOT * sizeof(int), stream);
    k_wt<<<(DF * DL + 255) / 256, 256, 0, stream>>>(W, Wt);
    k_user<<<(NUSER * DL) / 256, 256, 0, stream>>>(UP, embA, out);
    k_item<<<(NITEM + 63) / 64, 256, 0, stream>>>(F, Wt, B, embA, out);
    k_fill<<<(NNZ_ + 255) / 256, 256, 0, stream>>>(rows, cols, vals, cur, ecol, eval);

    k_spmm<<<(NTOT * DL) / 256, 256, 0, stream>>>(cur, ecol, eval, embA, embB, out);
    k_spmm<<<(NTOT * DL) / 256, 256, 0, stream>>>(cur, ecol, eval, embB, embA, out);
    k_spmm<<<(NTOT * DL) / 256, 256, 0, stream>>>(cur, ecol, eval, embA, embB, out);
}

// Round 2
// 542.679 us; speedup vs baseline: 2.1309x; 2.1309x over previous
//
#include <hip/hip_runtime.h>

#define NUSER 100000
#define NITEM 50000
#define NTOT  150000
#define DF    512
#define DL    64
#define NNZ_  2400000
#define CAP   64

// ---------------- users: L2-normalize rows, init emb + out ----------------
__global__ __launch_bounds__(256) void k_user(const float* __restrict__ up,
                                              float* __restrict__ emb,
                                              float* __restrict__ outp) {
    int t = blockIdx.x * 256 + threadIdx.x;
    int r = t >> 6;
    if (r >= NUSER) return;
    float v = up[t];
    float ss = v * v;
    #pragma unroll
    for (int m = 32; m >= 1; m >>= 1) ss += __shfl_xor(ss, m, 64);
    float scale = 1.0f / fmaxf(sqrtf(ss), 1e-12f);
    float o = v * scale;
    emb[t]  = o;
    outp[t] = 0.25f * o;  // embs_sum/4 accumulator init
}

// ---------------- items: GEMM (64 rows x 64 dims tile, K chunks of 64 in LDS) ----------------
#define KCH 64
__global__ __launch_bounds__(256) void k_item(const float* __restrict__ F,
                                              const float* __restrict__ W,
                                              const float* __restrict__ B,
                                              float* __restrict__ emb,
                                              float* __restrict__ outp) {
    __shared__ float ft[64][66];   // pad 66: r0-groups 4 rows apart -> 264 floats -> bank-shifted
    __shared__ float wt[KCH][64];  // W natural layout [k][d]
    int t = threadIdx.x;
    int block_r0 = blockIdx.x * 64;
    int d0 = (t & 15) * 4;
    int r0 = (t >> 4) * 4;
    float acc[4][4] = {};
    for (int kc = 0; kc < DF; kc += KCH) {
        // stage F tile: 64 rows x 64 k  (1024 float4, 4 per thread)
        #pragma unroll
        for (int i = 0; i < 4; ++i) {
            int li  = t + i * 256;      // 0..1023
            int row = li >> 4;          // 16 float4 per row
            int k4  = (li & 15) * 4;
            int gr  = block_r0 + row;
            float4 v = make_float4(0.f, 0.f, 0.f, 0.f);
            if (gr < NITEM) v = *(const float4*)&F[(size_t)gr * DF + kc + k4];
            *(float4*)&ft[row][k4] = v;
        }
        // stage W chunk: 64 k x 64 d (1024 float4, 4 per thread)
        #pragma unroll
        for (int i = 0; i < 4; ++i) {
            int li = t + i * 256;
            int k  = li >> 4;
            int dd = (li & 15) * 4;
            *(float4*)&wt[k][dd] = *(const float4*)&W[(size_t)(kc + k) * DL + dd];
        }
        __syncthreads();
        #pragma unroll 4
        for (int kk = 0; kk < KCH; kk += 4) {
            float4 w0 = *(const float4*)&wt[kk + 0][d0];
            float4 w1 = *(const float4*)&wt[kk + 1][d0];
            float4 w2 = *(const float4*)&wt[kk + 2][d0];
            float4 w3 = *(const float4*)&wt[kk + 3][d0];
            #pragma unroll
            for (int i = 0; i < 4; ++i) {
                float4 f = *(const float4*)&ft[r0 + i][kk];
                acc[i][0] += f.x * w0.x + f.y * w1.x + f.z * w2.x + f.w * w3.x;
                acc[i][1] += f.x * w0.y + f.y * w1.y + f.z * w2.y + f.w * w3.y;
                acc[i][2] += f.x * w0.z + f.y * w1.z + f.z * w2.z + f.w * w3.z;
                acc[i][3] += f.x * w0.w + f.y * w1.w + f.z * w2.w + f.w * w3.w;
            }
        }
        __syncthreads();
    }
    float b0 = B[d0], b1 = B[d0 + 1], b2 = B[d0 + 2], b3 = B[d0 + 3];
    #pragma unroll
    for (int i = 0; i < 4; ++i) {
        acc[i][0] += b0; acc[i][1] += b1; acc[i][2] += b2; acc[i][3] += b3;
        float ss = acc[i][0] * acc[i][0] + acc[i][1] * acc[i][1]
                 + acc[i][2] * acc[i][2] + acc[i][3] * acc[i][3];
        #pragma unroll
        for (int m = 8; m >= 1; m >>= 1) ss += __shfl_xor(ss, m, 64);  // 16 lanes/row
        float scale = 1.0f / fmaxf(sqrtf(ss), 1e-12f);
        int gr = block_r0 + r0 + i;
        if (gr < NITEM) {
            size_t o = (size_t)(NUSER + gr) * DL + d0;
            float4 v = make_float4(acc[i][0] * scale, acc[i][1] * scale,
                                   acc[i][2] * scale, acc[i][3] * scale);
            *(float4*)&emb[o] = v;
            float4 vo = make_float4(v.x * 0.25f, v.y * 0.25f, v.z * 0.25f, v.w * 0.25f);
            *(float4*)&outp[o] = vo;
        }
    }
}

// ---------------- bucket fill (fixed-capacity CSR substitute, packed int2) ----------------
__global__ __launch_bounds__(256) void k_fill(const int* __restrict__ rows,
                                              const int* __restrict__ cols,
                                              const float* __restrict__ vals,
                                              int* __restrict__ cur,
                                              int2* __restrict__ ecv) {
    int e = blockIdx.x * 256 + threadIdx.x;
    if (e >= NNZ_) return;
    int r = rows[e];
    int pos = atomicAdd(&cur[r], 1);
    if (pos < CAP) {
        ecv[(size_t)r * CAP + pos] = make_int2(cols[e], __float_as_int(vals[e]));
    }
}

// ---------------- SpMM layer: one wave per row, 4 edges in flight ----------------
__global__ __launch_bounds__(256) void k_spmm(const int* __restrict__ cur,
                                              const int2* __restrict__ ecv,
                                              const float* __restrict__ embIn,
                                              float* __restrict__ embOut,
                                              float* __restrict__ outp) {
    int wid  = (blockIdx.x * 256 + threadIdx.x) >> 6;
    int lane = threadIdx.x & 63;
    if (wid >= NTOT) return;
    int g  = lane >> 4;        // edge-group 0..3
    int d4 = (lane & 15) * 4;  // 16 lanes x float4 = 64 dims
    int cnt  = min(cur[wid], CAP);
    size_t base = (size_t)wid * CAP;
    float4 acc = make_float4(0.f, 0.f, 0.f, 0.f);
    for (int j = g; j < cnt; j += 4) {
        int2  cv = ecv[base + j];
        float v  = __int_as_float(cv.y);
        float4 e = *(const float4*)&embIn[(size_t)cv.x * DL + d4];
        acc.x += v * e.x; acc.y += v * e.y; acc.z += v * e.z; acc.w += v * e.w;
    }
    // reduce the 4 edge-groups (lanes xor 16, 32 hold same dims)
    #pragma unroll
    for (int m = 16; m <= 32; m <<= 1) {
        acc.x += __shfl_xor(acc.x, m, 64);
        acc.y += __shfl_xor(acc.y, m, 64);
        acc.z += __shfl_xor(acc.z, m, 64);
        acc.w += __shfl_xor(acc.w, m, 64);
    }
    if (g == 0) {
        size_t o = (size_t)wid * DL + d4;
        *(float4*)&embOut[o] = acc;
        float4 cu = *(const float4*)&outp[o];
        cu.x += 0.25f * acc.x; cu.y += 0.25f * acc.y;
        cu.z += 0.25f * acc.z; cu.w += 0.25f * acc.w;
        *(float4*)&outp[o] = cu;
    }
}

extern "C" void kernel_launch(void* const* d_in, const int* in_sizes, int n_in,
                              void* d_out, int out_size, void* d_ws, size_t ws_size,
                              hipStream_t stream) {
    const float* F    = (const float*)d_in[0];
    const float* UP   = (const float*)d_in[1];
    const float* W    = (const float*)d_in[2];
    const float* B    = (const float*)d_in[3];
    const int*   rows = (const int*)d_in[4];
    const int*   cols = (const int*)d_in[5];
    const float* vals = (const float*)d_in[6];
    float* out = (float*)d_out;

    // workspace carve (~154 MB)
    float* embA = (float*)d_ws;
    float* embB = embA + (size_t)NTOT * DL;
    int*   cur  = (int*)(embB + (size_t)NTOT * DL);
    int2*  ecv  = (int2*)(cur + NTOT);

    hipMemsetAsync(cur, 0, NTOT * sizeof(int), stream);
    k_user<<<(NUSER * DL) / 256, 256, 0, stream>>>(UP, embA, out);
    k_item<<<(NITEM + 63) / 64, 256, 0, stream>>>(F, W, B, embA, out);
    k_fill<<<(NNZ_ + 255) / 256, 256, 0, stream>>>(rows, cols, vals, cur, ecv);

    k_spmm<<<(NTOT * DL) / 256, 256, 0, stream>>>(cur, ecv, embA, embB, out);
    k_spmm<<<(NTOT * DL) / 256, 256, 0, stream>>>(cur, ecv, embB, embA, out);
    k_spmm<<<(NTOT * DL) / 256, 256, 0, stream>>>(cur, ecv, embA, embB, out);
}